// Round 1
// baseline (3079.787 us; speedup 1.0000x reference)
//
#include <hip/hip_runtime.h>
#include <math.h>

#define TID threadIdx.x

static constexpr int NN = 20000;
static constexpr int NE = 640000;
static constexpr int NT = 1000000;
static constexpr int C = 128;
static constexpr int E = 64;
static constexpr float CUT = 5.0f;
static constexpr float LN2 = 0.69314718055994530942f;

__device__ __forceinline__ float ssp(float x) {
    // softplus(x) - log(2), numerically stable
    return fmaxf(x, 0.0f) + log1pf(__expf(-fabsf(x))) - LN2;
}

__global__ __launch_bounds__(256) void k_zero(float* __restrict__ p, int n) {
    int i = blockIdx.x * 256 + TID;
    if (i < n) p[i] = 0.0f;
}

// out[r][c] = sum_k A[r][k] * W[k][c]   (A: nrows x 128, W: 128 x 128)
__global__ __launch_bounds__(256) void k_gemm128(const float* __restrict__ A,
                                                 const float* __restrict__ W,
                                                 float* __restrict__ out, int nrows) {
    __shared__ float wL[C * C];   // 64 KB
    __shared__ float aL[8][C];    // 4 KB
    for (int i = TID; i < C * C; i += 256) wL[i] = W[i];
    const int rg = TID >> 5;            // 0..7 : row within chunk
    const int c4 = (TID & 31) << 2;     // 0,4,...,124
    for (int base = blockIdx.x * 8; base < nrows; base += gridDim.x * 8) {
        __syncthreads();
        for (int i = TID; i < 8 * C; i += 256) {
            int r = base + (i >> 7);
            aL[i >> 7][i & 127] = (r < nrows) ? A[(size_t)r * C + (i & 127)] : 0.0f;
        }
        __syncthreads();
        float4 acc = {0.f, 0.f, 0.f, 0.f};
        #pragma unroll 16
        for (int k = 0; k < C; ++k) {
            float a = aL[rg][k];
            const float4 w4 = *(const float4*)&wL[k * C + c4];
            acc.x = fmaf(a, w4.x, acc.x);
            acc.y = fmaf(a, w4.y, acc.y);
            acc.z = fmaf(a, w4.z, acc.z);
            acc.w = fmaf(a, w4.w, acc.w);
        }
        int r = base + rg;
        if (r < nrows) *(float4*)&out[(size_t)r * C + c4] = acc;
    }
}

// Per-edge: rb(d) -> ssp(rb@W2b1) -> @W2b2 -> * h[nl1[e]] -> atomicAdd agg[nl0[e]]
__global__ __launch_bounds__(256) void k_edges(const float* __restrict__ dist,
                                               const int* __restrict__ nl0,
                                               const int* __restrict__ nl1,
                                               const float* __restrict__ h,
                                               const float* __restrict__ W2b1,
                                               const float* __restrict__ W2b2,
                                               float* __restrict__ agg) {
    __shared__ float w1[E * E];     // 16 KB
    __shared__ float w2[E * C];     // 32 KB
    __shared__ float rbL[8][E];     // 2 KB
    __shared__ float t1L[8][E];     // 2 KB
    __shared__ int n0s[8], n1s[8];
    for (int i = TID; i < E * E; i += 256) w1[i] = W2b1[i];
    for (int i = TID; i < E * C; i += 256) w2[i] = W2b2[i];
    const int jj = TID & 63;
    const int esA = TID >> 6;           // 0..3
    const int eg = TID >> 5;            // 0..7
    const int c4 = (TID & 31) << 2;
    const float gamma = 81.92f;         // 1 / (2*(5/64)^2)
    const float cstep = CUT / 63.0f;    // linspace(0, 5, 64) spacing
    for (int base = blockIdx.x * 8; base < NE; base += gridDim.x * 8) {
        __syncthreads();
        if (TID < 8) {
            int e = base + TID;
            n0s[TID] = (e < NE) ? nl0[e] : 0;
            n1s[TID] = (e < NE) ? nl1[e] : 0;
        }
        #pragma unroll
        for (int s = 0; s < 2; ++s) {
            int es = esA + s * 4;
            int e = base + es;
            float d = (e < NE) ? dist[e] : 2.0f * CUT;
            float cen = (float)jj * cstep;
            float dd = d - cen;
            float g = __expf(-gamma * dd * dd);
            float cv = (d < CUT) ? 0.5f * (1.0f + __cosf((float)M_PI * d / CUT)) : 0.0f;
            rbL[es][jj] = g * cv;
        }
        __syncthreads();
        #pragma unroll
        for (int s = 0; s < 2; ++s) {
            int es = esA + s * 4;
            float acc = 0.0f;
            #pragma unroll 16
            for (int k = 0; k < E; ++k)
                acc = fmaf(rbL[es][k], w1[k * E + jj], acc);
            t1L[es][jj] = ssp(acc);
        }
        __syncthreads();
        {
            float4 acc = {0.f, 0.f, 0.f, 0.f};
            #pragma unroll
            for (int j = 0; j < E; j += 4) {
                const float4 tv = *(const float4*)&t1L[eg][j];
                const float4 wa = *(const float4*)&w2[(j + 0) * C + c4];
                const float4 wb = *(const float4*)&w2[(j + 1) * C + c4];
                const float4 wc = *(const float4*)&w2[(j + 2) * C + c4];
                const float4 wd = *(const float4*)&w2[(j + 3) * C + c4];
                acc.x = fmaf(tv.x, wa.x, acc.x);
                acc.y = fmaf(tv.x, wa.y, acc.y);
                acc.z = fmaf(tv.x, wa.z, acc.z);
                acc.w = fmaf(tv.x, wa.w, acc.w);
                acc.x = fmaf(tv.y, wb.x, acc.x);
                acc.y = fmaf(tv.y, wb.y, acc.y);
                acc.z = fmaf(tv.y, wb.z, acc.z);
                acc.w = fmaf(tv.y, wb.w, acc.w);
                acc.x = fmaf(tv.z, wc.x, acc.x);
                acc.y = fmaf(tv.z, wc.y, acc.y);
                acc.z = fmaf(tv.z, wc.z, acc.z);
                acc.w = fmaf(tv.z, wc.w, acc.w);
                acc.x = fmaf(tv.w, wd.x, acc.x);
                acc.y = fmaf(tv.w, wd.y, acc.y);
                acc.z = fmaf(tv.w, wd.z, acc.z);
                acc.w = fmaf(tv.w, wd.w, acc.w);
            }
            int e = base + eg;
            if (e < NE) {
                const float4 h4 = *(const float4*)&h[(size_t)n1s[eg] * C + c4];
                float* dst = &agg[(size_t)n0s[eg] * C + c4];
                unsafeAtomicAdd(dst + 0, acc.x * h4.x);
                unsafeAtomicAdd(dst + 1, acc.y * h4.y);
                unsafeAtomicAdd(dst + 2, acc.z * h4.z);
                unsafeAtomicAdd(dst + 3, acc.w * h4.w);
            }
        }
    }
}

// Per-triplet: u = ssp(tbf@W3b1) ; w3 = u@W3b2 ; msg = h[t1]*w3 -> atomicAdd agg[nl0[t1]]
__global__ __launch_bounds__(256) void k_trip(const int* __restrict__ tidx,
                                              const float* __restrict__ angles,
                                              const float* __restrict__ rij,
                                              const float* __restrict__ rik,
                                              const int* __restrict__ nl0,
                                              const float* __restrict__ h,
                                              const float* __restrict__ W3b1,
                                              const float* __restrict__ W3b2,
                                              float* __restrict__ agg) {
    __shared__ float w1[3 * 64];    // 768 B
    __shared__ float w2[64 * C];    // 32 KB
    __shared__ float uL[8][64];     // 2 KB
    __shared__ int n0s[8], h1s[8];
    for (int i = TID; i < 3 * 64; i += 256) w1[i] = W3b1[i];
    for (int i = TID; i < 64 * C; i += 256) w2[i] = W3b2[i];
    const int jj = TID & 63;
    const int esA = TID >> 6;
    const int eg = TID >> 5;
    const int c4 = (TID & 31) << 2;
    for (int base = blockIdx.x * 8; base < NT; base += gridDim.x * 8) {
        __syncthreads();
        if (TID < 8) {
            int t = base + TID;
            int t1 = (t < NT) ? tidx[t * 3 + 1] : 0;
            h1s[TID] = t1;
            n0s[TID] = nl0[t1];
        }
        #pragma unroll
        for (int s = 0; s < 2; ++s) {
            int es = esA + s * 4;
            int t = base + es;
            float an = (t < NT) ? angles[t] : 0.0f;
            float ri = (t < NT) ? rij[t] : 0.0f;
            float rk = (t < NT) ? rik[t] : 0.0f;
            float ca = __cosf(an);
            float x = ri * w1[jj] + rk * w1[64 + jj] + ca * w1[128 + jj];
            uL[es][jj] = ssp(x);
        }
        __syncthreads();
        {
            float4 acc = {0.f, 0.f, 0.f, 0.f};
            #pragma unroll
            for (int j = 0; j < 64; j += 4) {
                const float4 tv = *(const float4*)&uL[eg][j];
                const float4 wa = *(const float4*)&w2[(j + 0) * C + c4];
                const float4 wb = *(const float4*)&w2[(j + 1) * C + c4];
                const float4 wc = *(const float4*)&w2[(j + 2) * C + c4];
                const float4 wd = *(const float4*)&w2[(j + 3) * C + c4];
                acc.x = fmaf(tv.x, wa.x, acc.x);
                acc.y = fmaf(tv.x, wa.y, acc.y);
                acc.z = fmaf(tv.x, wa.z, acc.z);
                acc.w = fmaf(tv.x, wa.w, acc.w);
                acc.x = fmaf(tv.y, wb.x, acc.x);
                acc.y = fmaf(tv.y, wb.y, acc.y);
                acc.z = fmaf(tv.y, wb.z, acc.z);
                acc.w = fmaf(tv.y, wb.w, acc.w);
                acc.x = fmaf(tv.z, wc.x, acc.x);
                acc.y = fmaf(tv.z, wc.y, acc.y);
                acc.z = fmaf(tv.z, wc.z, acc.z);
                acc.w = fmaf(tv.z, wc.w, acc.w);
                acc.x = fmaf(tv.w, wd.x, acc.x);
                acc.y = fmaf(tv.w, wd.y, acc.y);
                acc.z = fmaf(tv.w, wd.z, acc.z);
                acc.w = fmaf(tv.w, wd.w, acc.w);
            }
            int t = base + eg;
            if (t < NT) {
                const float4 h4 = *(const float4*)&h[(size_t)h1s[eg] * C + c4];
                float* dst = &agg[(size_t)n0s[eg] * C + c4];
                unsafeAtomicAdd(dst + 0, acc.x * h4.x);
                unsafeAtomicAdd(dst + 1, acc.y * h4.y);
                unsafeAtomicAdd(dst + 2, acc.z * h4.z);
                unsafeAtomicAdd(dst + 3, acc.w * h4.w);
            }
        }
    }
}

extern "C" void kernel_launch(void* const* d_in, const int* in_sizes, int n_in,
                              void* d_out, int out_size, void* d_ws, size_t ws_size,
                              hipStream_t stream) {
    const float* features = (const float*)d_in[0];
    const float* ndist    = (const float*)d_in[1];
    const int*   nlist    = (const int*)d_in[2];
    const int*   tidx     = (const int*)d_in[3];
    const float* angles   = (const float*)d_in[4];
    const float* rij      = (const float*)d_in[5];
    const float* rik      = (const float*)d_in[6];
    const float* W_pre    = (const float*)d_in[7];
    const float* W2b1     = (const float*)d_in[8];
    const float* W2b2     = (const float*)d_in[9];
    const float* W3b1     = (const float*)d_in[10];
    const float* W3b2     = (const float*)d_in[11];
    const float* W_post   = (const float*)d_in[12];
    float* out = (float*)d_out;

    float* h   = (float*)d_ws;                  // 20000*128 f32 = 10.24 MB
    float* agg = h + (size_t)NN * C;            // 20000*128 f32 = 10.24 MB
    const int* nl0 = nlist;
    const int* nl1 = nlist + NE;

    hipLaunchKernelGGL(k_zero, dim3((NN * C + 255) / 256), dim3(256), 0, stream,
                       agg, NN * C);
    hipLaunchKernelGGL(k_gemm128, dim3(2048), dim3(256), 0, stream,
                       features, W_pre, h, NN);
    hipLaunchKernelGGL(k_edges, dim3(2560), dim3(256), 0, stream,
                       ndist, nl0, nl1, h, W2b1, W2b2, agg);
    hipLaunchKernelGGL(k_trip, dim3(2560), dim3(256), 0, stream,
                       tidx, angles, rij, rik, nl0, h, W3b1, W3b2, agg);
    hipLaunchKernelGGL(k_gemm128, dim3(2048), dim3(256), 0, stream,
                       agg, W_post, out, NN);
}

// Round 2
// 924.305 us; speedup vs baseline: 3.3320x; 3.3320x over previous
//
#include <hip/hip_runtime.h>
#include <math.h>

#define TID threadIdx.x

static constexpr int NN = 20000;
static constexpr int NE = 640000;
static constexpr int NT = 1000000;
static constexpr int C = 128;
static constexpr int E = 64;
static constexpr float CUT = 5.0f;
static constexpr float LN2 = 0.69314718055994530942f;

__device__ __forceinline__ float ssp(float x) {
    // softplus(x) - log(2), numerically stable, fast-math friendly
    return fmaxf(x, 0.0f) + __logf(1.0f + __expf(-fabsf(x))) - LN2;
}

__global__ __launch_bounds__(256) void k_zero(float* __restrict__ p, int n) {
    int i = blockIdx.x * 256 + TID;
    if (i < n) p[i] = 0.0f;
}

// out[r][c] = sum_k A[r][k] * W[k][c]   (A: nrows x 128, W: 128 x 128)
__global__ __launch_bounds__(256) void k_gemm128(const float* __restrict__ A,
                                                 const float* __restrict__ W,
                                                 float* __restrict__ out, int nrows) {
    __shared__ float wL[C * C];   // 64 KB
    __shared__ float aL[8][C];    // 4 KB
    for (int i = TID; i < C * C; i += 256) wL[i] = W[i];
    const int rg = TID >> 5;
    const int c4 = (TID & 31) << 2;
    for (int base = blockIdx.x * 8; base < nrows; base += gridDim.x * 8) {
        __syncthreads();
        for (int i = TID; i < 8 * C; i += 256) {
            int r = base + (i >> 7);
            aL[i >> 7][i & 127] = (r < nrows) ? A[(size_t)r * C + (i & 127)] : 0.0f;
        }
        __syncthreads();
        float4 acc = {0.f, 0.f, 0.f, 0.f};
        #pragma unroll 16
        for (int k = 0; k < C; ++k) {
            float a = aL[rg][k];
            const float4 w4 = *(const float4*)&wL[k * C + c4];
            acc.x = fmaf(a, w4.x, acc.x);
            acc.y = fmaf(a, w4.y, acc.y);
            acc.z = fmaf(a, w4.z, acc.z);
            acc.w = fmaf(a, w4.w, acc.w);
        }
        int r = base + rg;
        if (r < nrows) *(float4*)&out[(size_t)r * C + c4] = acc;
    }
}

// Histograms of edge destinations (nl0) and triplet centers (t1)
__global__ __launch_bounds__(256) void k_hist(const int* __restrict__ nl0,
                                              const int* __restrict__ tidx,
                                              int* __restrict__ histE,
                                              int* __restrict__ histT) {
    for (int i = blockIdx.x * 256 + TID; i < NT; i += gridDim.x * 256) {
        if (i < NE) atomicAdd(&histE[nl0[i]], 1);
        atomicAdd(&histT[tidx[3 * i + 1]], 1);
    }
}

__device__ void scan_one(const int* __restrict__ hist, int* __restrict__ start,
                         int* __restrict__ cur, int n) {
    __shared__ int wsum[16];
    __shared__ int carryS;
    const int lane = TID & 63;
    const int wv = TID >> 6;
    if (TID == 0) carryS = 0;
    __syncthreads();
    for (int base = 0; base < n; base += 1024) {
        int i = base + TID;
        int v = (i < n) ? hist[i] : 0;
        int acc = v;
        #pragma unroll
        for (int off = 1; off < 64; off <<= 1) {
            int t = __shfl_up(acc, off, 64);
            if (lane >= off) acc += t;
        }
        if (lane == 63) wsum[wv] = acc;
        __syncthreads();
        int woff = 0;
        for (int w = 0; w < wv; ++w) woff += wsum[w];
        int carry = carryS;
        int excl = carry + woff + acc - v;
        if (i < n) { start[i] = excl; cur[i] = excl; }
        __syncthreads();
        if (TID == 1023) carryS = excl + v;
        __syncthreads();
    }
}

__global__ __launch_bounds__(1024) void k_scan2(const int* __restrict__ hE, int* __restrict__ sE,
                                                int* __restrict__ cE,
                                                const int* __restrict__ hT, int* __restrict__ sT,
                                                int* __restrict__ cT) {
    if (blockIdx.x == 0) scan_one(hE, sE, cE, NN);
    else                 scan_one(hT, sT, cT, NN);
}

__global__ __launch_bounds__(256) void k_scatter(const int* __restrict__ nl0,
                                                 const int* __restrict__ tidx,
                                                 int* __restrict__ curE, int* __restrict__ curT,
                                                 int* __restrict__ permE, int* __restrict__ permT) {
    for (int i = blockIdx.x * 256 + TID; i < NT; i += gridDim.x * 256) {
        if (i < NE) {
            int pos = atomicAdd(&curE[nl0[i]], 1);
            permE[pos] = i;
        }
        int pos = atomicAdd(&curT[tidx[3 * i + 1]], 1);
        permT[pos] = i;
    }
}

// One wave per node r: usum = sum over its triplets of ssp(tbf @ W3b1); write uacc[r]
__global__ __launch_bounds__(256) void k_trip_seg(const int* __restrict__ permT,
                                                  const int* __restrict__ startT,
                                                  const int* __restrict__ histT,
                                                  const float* __restrict__ angles,
                                                  const float* __restrict__ rij,
                                                  const float* __restrict__ rik,
                                                  const float* __restrict__ W3b1,
                                                  float* __restrict__ uacc) {
    const int lane = TID & 63;
    const int wv = TID >> 6;
    const float w1a = W3b1[lane];
    const float w1b = W3b1[64 + lane];
    const float w1c = W3b1[128 + lane];
    for (int r = blockIdx.x * 4 + wv; r < NN; r += gridDim.x * 4) {
        const int s0 = startT[r];
        const int cnt = histT[r];
        float usum = 0.f;
        for (int base = 0; base < cnt; base += 64) {
            const int n = min(64, cnt - base);
            float a = 0.f, ri = 0.f, rk = 0.f;
            if (lane < n) {
                int p = permT[s0 + base + lane];
                a = angles[p]; ri = rij[p]; rk = rik[p];
            }
            float ca = __cosf(a);
            for (int i = 0; i < n; ++i) {
                float riB = __shfl(ri, i, 64);
                float rkB = __shfl(rk, i, 64);
                float caB = __shfl(ca, i, 64);
                float x = fmaf(riB, w1a, fmaf(rkB, w1b, caB * w1c));
                usum += ssp(x);
            }
        }
        uacc[(size_t)r * 64 + lane] = usum;
    }
}

#define FMA16(o, tv, wbase, j)                                        \
    do {                                                              \
        const float4 wa = *(const float4*)&(wbase)[((j) + 0) * C + c4]; \
        const float4 wb = *(const float4*)&(wbase)[((j) + 1) * C + c4]; \
        const float4 wc = *(const float4*)&(wbase)[((j) + 2) * C + c4]; \
        const float4 wd = *(const float4*)&(wbase)[((j) + 3) * C + c4]; \
        o.x = fmaf(tv.x, wa.x, o.x); o.y = fmaf(tv.x, wa.y, o.y);     \
        o.z = fmaf(tv.x, wa.z, o.z); o.w = fmaf(tv.x, wa.w, o.w);     \
        o.x = fmaf(tv.y, wb.x, o.x); o.y = fmaf(tv.y, wb.y, o.y);     \
        o.z = fmaf(tv.y, wb.z, o.z); o.w = fmaf(tv.y, wb.w, o.w);     \
        o.x = fmaf(tv.z, wc.x, o.x); o.y = fmaf(tv.z, wc.y, o.y);     \
        o.z = fmaf(tv.z, wc.z, o.z); o.w = fmaf(tv.z, wc.w, o.w);     \
        o.x = fmaf(tv.w, wd.x, o.x); o.y = fmaf(tv.w, wd.y, o.y);     \
        o.z = fmaf(tv.w, wd.z, o.z); o.w = fmaf(tv.w, wd.w, o.w);     \
    } while (0)

// One block per node r: sum of two_body over its edges, written once (no atomics).
__global__ __launch_bounds__(256) void k_edges_seg(const int* __restrict__ permE,
                                                   const int* __restrict__ startE,
                                                   const int* __restrict__ histE,
                                                   const float* __restrict__ dist,
                                                   const int* __restrict__ nl1,
                                                   const float* __restrict__ h,
                                                   const float* __restrict__ W2b1,
                                                   const float* __restrict__ W2b2,
                                                   float* __restrict__ agg) {
    __shared__ float w1[E * E];      // 16 KB
    __shared__ float w2[E * C];      // 32 KB
    __shared__ float rbt[8][128];    // 4 KB: [e][0:64]=rb, [e][64:128]=hidden; reused as reduce buf
    __shared__ float dsh[8];
    __shared__ int n1s[8];
    for (int i = TID; i < E * E; i += 256) w1[i] = W2b1[i];
    for (int i = TID; i < E * C; i += 256) w2[i] = W2b2[i];
    const int jj = TID & 63;
    const int esA = TID >> 6;
    const int eg = TID >> 5;
    const int c4 = (TID & 31) << 2;
    const float gamma = 81.92f;           // 1 / (2*(5/64)^2)
    const float cstep = CUT / 63.0f;
    for (int r = blockIdx.x; r < NN; r += gridDim.x) {
        const int s0 = startE[r];
        const int cnt = histE[r];
        float4 acc = {0.f, 0.f, 0.f, 0.f};
        for (int it = 0; it < cnt; it += 8) {
            __syncthreads();
            if (TID < 8) {
                int k = it + TID;
                float d = 2.0f * CUT; int n1 = 0;
                if (k < cnt) { int e = permE[s0 + k]; d = dist[e]; n1 = nl1[e]; }
                dsh[TID] = d; n1s[TID] = n1;
            }
            __syncthreads();
            #pragma unroll
            for (int s = 0; s < 2; ++s) {
                int es = esA + 4 * s;
                float d = dsh[es];
                float dd = d - (float)jj * cstep;
                float g = __expf(-gamma * dd * dd);
                float cv = (d < CUT) ? 0.5f * (1.0f + __cosf((float)M_PI * d / CUT)) : 0.0f;
                rbt[es][jj] = g * cv;
            }
            __syncthreads();
            #pragma unroll
            for (int s = 0; s < 2; ++s) {
                int es = esA + 4 * s;
                float a = 0.f;
                #pragma unroll 16
                for (int k = 0; k < E; ++k)
                    a = fmaf(rbt[es][k], w1[k * E + jj], a);
                rbt[es][64 + jj] = ssp(a);    // disjoint halves: no extra barrier needed
            }
            __syncthreads();
            {
                float4 o = {0.f, 0.f, 0.f, 0.f};
                #pragma unroll
                for (int j = 0; j < E; j += 4) {
                    const float4 tv = *(const float4*)&rbt[eg][64 + j];
                    FMA16(o, tv, w2, j);
                }
                const float4 h4 = *(const float4*)&h[(size_t)n1s[eg] * C + c4];
                acc.x = fmaf(o.x, h4.x, acc.x);
                acc.y = fmaf(o.y, h4.y, acc.y);
                acc.z = fmaf(o.z, h4.z, acc.z);
                acc.w = fmaf(o.w, h4.w, acc.w);
            }
        }
        // reduce 8 groups -> one row, single non-atomic write
        __syncthreads();
        *(float4*)&rbt[eg][c4] = acc;
        __syncthreads();
        if (TID < 128) {
            float v = 0.f;
            #pragma unroll
            for (int g = 0; g < 8; ++g) v += rbt[g][TID];
            agg[(size_t)r * C + TID] = v;
        }
    }
}

// Per pseudo-edge r<NN: w3 = uacc[r] @ W3b2 ; agg[nl0[r]] += h[r] * w3
__global__ __launch_bounds__(256) void k_node_final(const float* __restrict__ uacc,
                                                    const float* __restrict__ W3b2,
                                                    const float* __restrict__ h,
                                                    const int* __restrict__ nl0,
                                                    float* __restrict__ agg) {
    __shared__ float w2[64 * C];   // 32 KB
    __shared__ float uL[8][64];    // 2 KB
    for (int i = TID; i < 64 * C; i += 256) w2[i] = W3b2[i];
    const int eg = TID >> 5;
    const int c4 = (TID & 31) << 2;
    for (int base = blockIdx.x * 8; base < NN; base += gridDim.x * 8) {
        __syncthreads();
        if (TID < 128) {
            int row = TID >> 4, col = (TID & 15) << 2;
            *(float4*)&uL[row][col] = *(const float4*)&uacc[(size_t)(base + row) * 64 + col];
        }
        __syncthreads();
        float4 o = {0.f, 0.f, 0.f, 0.f};
        #pragma unroll
        for (int j = 0; j < 64; j += 4) {
            const float4 tv = *(const float4*)&uL[eg][j];
            FMA16(o, tv, w2, j);
        }
        const int r = base + eg;
        const float4 h4 = *(const float4*)&h[(size_t)r * C + c4];
        float* dst = &agg[(size_t)nl0[r] * C + c4];
        unsafeAtomicAdd(dst + 0, o.x * h4.x);
        unsafeAtomicAdd(dst + 1, o.y * h4.y);
        unsafeAtomicAdd(dst + 2, o.z * h4.z);
        unsafeAtomicAdd(dst + 3, o.w * h4.w);
    }
}

extern "C" void kernel_launch(void* const* d_in, const int* in_sizes, int n_in,
                              void* d_out, int out_size, void* d_ws, size_t ws_size,
                              hipStream_t stream) {
    const float* features = (const float*)d_in[0];
    const float* ndist    = (const float*)d_in[1];
    const int*   nlist    = (const int*)d_in[2];
    const int*   tidx     = (const int*)d_in[3];
    const float* angles   = (const float*)d_in[4];
    const float* rij      = (const float*)d_in[5];
    const float* rik      = (const float*)d_in[6];
    const float* W_pre    = (const float*)d_in[7];
    const float* W2b1     = (const float*)d_in[8];
    const float* W2b2     = (const float*)d_in[9];
    const float* W3b1     = (const float*)d_in[10];
    const float* W3b2     = (const float*)d_in[11];
    const float* W_post   = (const float*)d_in[12];
    float* out = (float*)d_out;

    float* h    = (float*)d_ws;                  // NN*C
    float* agg  = h + (size_t)NN * C;            // NN*C
    float* uacc = agg + (size_t)NN * C;          // NN*64
    int* permE  = (int*)(uacc + (size_t)NN * 64);// NE
    int* permT  = permE + NE;                    // NT
    int* histE  = permT + NT;                    // NN
    int* histT  = histE + NN;                    // NN
    int* startE = histT + NN;                    // NN
    int* startT = startE + NN;                   // NN
    int* curE   = startT + NN;                   // NN
    int* curT   = curE + NN;                     // NN
    const int* nl0 = nlist;
    const int* nl1 = nlist + NE;

    hipLaunchKernelGGL(k_zero, dim3((2 * NN + 255) / 256), dim3(256), 0, stream,
                       (float*)histE, 2 * NN);
    hipLaunchKernelGGL(k_gemm128, dim3(2500), dim3(256), 0, stream,
                       features, W_pre, h, NN);
    hipLaunchKernelGGL(k_hist, dim3(2048), dim3(256), 0, stream,
                       nl0, tidx, histE, histT);
    hipLaunchKernelGGL(k_scan2, dim3(2), dim3(1024), 0, stream,
                       histE, startE, curE, histT, startT, curT);
    hipLaunchKernelGGL(k_scatter, dim3(2048), dim3(256), 0, stream,
                       nl0, tidx, curE, curT, permE, permT);
    hipLaunchKernelGGL(k_trip_seg, dim3(2560), dim3(256), 0, stream,
                       permT, startT, histT, angles, rij, rik, W3b1, uacc);
    hipLaunchKernelGGL(k_edges_seg, dim3(2560), dim3(256), 0, stream,
                       permE, startE, histE, ndist, nl1, h, W2b1, W2b2, agg);
    hipLaunchKernelGGL(k_node_final, dim3(2500), dim3(256), 0, stream,
                       uacc, W3b2, h, nl0, agg);
    hipLaunchKernelGGL(k_gemm128, dim3(2500), dim3(256), 0, stream,
                       agg, W_post, out, NN);
}

// Round 3
// 594.614 us; speedup vs baseline: 5.1795x; 1.5545x over previous
//
#include <hip/hip_runtime.h>
#include <math.h>

#define TID threadIdx.x

typedef float f32x4 __attribute__((ext_vector_type(4)));
typedef short s16x8 __attribute__((ext_vector_type(8)));

static constexpr int NN = 20000;
static constexpr int NE = 640000;
static constexpr int NT = 1000000;
static constexpr int C = 128;
static constexpr int E = 64;
static constexpr float CUT = 5.0f;
static constexpr float LN2 = 0.69314718055994530942f;

__device__ __forceinline__ float ssp(float x) {
    return fmaxf(x, 0.0f) + __logf(1.0f + __expf(-fabsf(x))) - LN2;
}

__device__ __forceinline__ ushort f2bf(float x) {
    // round-to-nearest-even f32 -> bf16
    uint u = __float_as_uint(x);
    return (ushort)((u + 0x7FFFu + ((u >> 16) & 1u)) >> 16);
}

__global__ __launch_bounds__(256) void k_zero(float* __restrict__ p, int n) {
    int i = blockIdx.x * 256 + TID;
    if (i < n) p[i] = 0.0f;
}

// out[r][c] = sum_k A[r][k] * W[k][c]   (A: nrows x 128, W: 128 x 128)
__global__ __launch_bounds__(256) void k_gemm128(const float* __restrict__ A,
                                                 const float* __restrict__ W,
                                                 float* __restrict__ out, int nrows) {
    __shared__ float wL[C * C];
    __shared__ float aL[8][C];
    for (int i = TID; i < C * C; i += 256) wL[i] = W[i];
    const int rg = TID >> 5;
    const int c4 = (TID & 31) << 2;
    for (int base = blockIdx.x * 8; base < nrows; base += gridDim.x * 8) {
        __syncthreads();
        for (int i = TID; i < 8 * C; i += 256) {
            int r = base + (i >> 7);
            aL[i >> 7][i & 127] = (r < nrows) ? A[(size_t)r * C + (i & 127)] : 0.0f;
        }
        __syncthreads();
        float4 acc = {0.f, 0.f, 0.f, 0.f};
        #pragma unroll 16
        for (int k = 0; k < C; ++k) {
            float a = aL[rg][k];
            const float4 w4 = *(const float4*)&wL[k * C + c4];
            acc.x = fmaf(a, w4.x, acc.x);
            acc.y = fmaf(a, w4.y, acc.y);
            acc.z = fmaf(a, w4.z, acc.z);
            acc.w = fmaf(a, w4.w, acc.w);
        }
        int r = base + rg;
        if (r < nrows) *(float4*)&out[(size_t)r * C + c4] = acc;
    }
}

__global__ __launch_bounds__(256) void k_hist(const int* __restrict__ nl0,
                                              const int* __restrict__ tidx,
                                              int* __restrict__ histE,
                                              int* __restrict__ histT) {
    for (int i = blockIdx.x * 256 + TID; i < NT; i += gridDim.x * 256) {
        if (i < NE) atomicAdd(&histE[nl0[i]], 1);
        atomicAdd(&histT[tidx[3 * i + 1]], 1);
    }
}

__device__ void scan_one(const int* __restrict__ hist, int* __restrict__ start,
                         int* __restrict__ cur, int n) {
    __shared__ int wsum[16];
    __shared__ int carryS;
    const int lane = TID & 63;
    const int wv = TID >> 6;
    if (TID == 0) carryS = 0;
    __syncthreads();
    for (int base = 0; base < n; base += 1024) {
        int i = base + TID;
        int v = (i < n) ? hist[i] : 0;
        int acc = v;
        #pragma unroll
        for (int off = 1; off < 64; off <<= 1) {
            int t = __shfl_up(acc, off, 64);
            if (lane >= off) acc += t;
        }
        if (lane == 63) wsum[wv] = acc;
        __syncthreads();
        int woff = 0;
        for (int w = 0; w < wv; ++w) woff += wsum[w];
        int carry = carryS;
        int excl = carry + woff + acc - v;
        if (i < n) { start[i] = excl; cur[i] = excl; }
        __syncthreads();
        if (TID == 1023) carryS = excl + v;
        __syncthreads();
    }
}

__global__ __launch_bounds__(1024) void k_scan2(const int* __restrict__ hE, int* __restrict__ sE,
                                                int* __restrict__ cE,
                                                const int* __restrict__ hT, int* __restrict__ sT,
                                                int* __restrict__ cT) {
    if (blockIdx.x == 0) scan_one(hE, sE, cE, NN);
    else                 scan_one(hT, sT, cT, NN);
}

__global__ __launch_bounds__(256) void k_scatter(const int* __restrict__ nl0,
                                                 const int* __restrict__ tidx,
                                                 int* __restrict__ curE, int* __restrict__ curT,
                                                 int* __restrict__ permE, int* __restrict__ permT) {
    for (int i = blockIdx.x * 256 + TID; i < NT; i += gridDim.x * 256) {
        if (i < NE) {
            int pos = atomicAdd(&curE[nl0[i]], 1);
            permE[pos] = i;
        }
        int pos = atomicAdd(&curT[tidx[3 * i + 1]], 1);
        permT[pos] = i;
    }
}

// One wave per node r: usum = sum over its triplets of ssp(tbf @ W3b1); write uacc[r]
__global__ __launch_bounds__(256) void k_trip_seg(const int* __restrict__ permT,
                                                  const int* __restrict__ startT,
                                                  const int* __restrict__ histT,
                                                  const float* __restrict__ angles,
                                                  const float* __restrict__ rij,
                                                  const float* __restrict__ rik,
                                                  const float* __restrict__ W3b1,
                                                  float* __restrict__ uacc) {
    const int lane = TID & 63;
    const int wv = TID >> 6;
    const float w1a = W3b1[lane];
    const float w1b = W3b1[64 + lane];
    const float w1c = W3b1[128 + lane];
    for (int r = blockIdx.x * 4 + wv; r < NN; r += gridDim.x * 4) {
        const int s0 = startT[r];
        const int cnt = histT[r];
        float usum = 0.f;
        for (int base = 0; base < cnt; base += 64) {
            const int n = min(64, cnt - base);
            float a = 0.f, ri = 0.f, rk = 0.f;
            if (lane < n) {
                int p = permT[s0 + base + lane];
                a = angles[p]; ri = rij[p]; rk = rik[p];
            }
            float ca = __cosf(a);
            for (int i = 0; i < n; ++i) {
                float riB = __shfl(ri, i, 64);
                float rkB = __shfl(rk, i, 64);
                float caB = __shfl(ca, i, 64);
                float x = fmaf(riB, w1a, fmaf(rkB, w1b, caB * w1c));
                usum += ssp(x);
            }
        }
        uacc[(size_t)r * 64 + lane] = usum;
    }
}

// MFMA edge kernel: 64 sorted edges per chunk.
// rb(64x64) -> GEMM1 @W2b1 -> ssp -> GEMM2 @W2b2 -> *h[nl1] -> run-segmented atomic agg
__global__ __launch_bounds__(256) void k_edges_mfma(const int* __restrict__ permE,
                                                    const float* __restrict__ dist,
                                                    const int* __restrict__ nl0,
                                                    const int* __restrict__ nl1,
                                                    const float* __restrict__ h,
                                                    const float* __restrict__ W2b1,
                                                    const float* __restrict__ W2b2,
                                                    float* __restrict__ agg) {
    __shared__ __align__(16) short w1f[2][4][64][8];   // 8 KB  B-frags of W2b1
    __shared__ __align__(16) short w2f[2][8][64][8];   // 16 KB B-frags of W2b2
    __shared__ __align__(16) short aF[4][2][64][8];    // 8 KB  A-frags (rb, then t1)
    __shared__ short outL[64 * 132];                   // 16.9 KB bf16 out tile (padded)
    __shared__ float dsh[64], cvsh[64];
    __shared__ int n0sh[64], n1sh[64];

    const int l = TID & 63;
    const int w = TID >> 6;

    // Prepack weights into B-fragment layout: lane ln holds B[k=(ln>>4)*8+j][col=ln&15]
    for (int idx = TID; idx < 512; idx += 256) {
        int kb = idx >> 8, nb = (idx >> 6) & 3, ln = idx & 63;
        s16x8 v;
        #pragma unroll
        for (int j = 0; j < 8; ++j) {
            int k = kb * 32 + (ln >> 4) * 8 + j;
            int col = nb * 16 + (ln & 15);
            v[j] = (short)f2bf(W2b1[k * E + col]);
        }
        *(s16x8*)&w1f[kb][nb][ln][0] = v;
    }
    for (int idx = TID; idx < 1024; idx += 256) {
        int kb = idx >> 9, nb = (idx >> 6) & 7, ln = idx & 63;
        s16x8 v;
        #pragma unroll
        for (int j = 0; j < 8; ++j) {
            int k = kb * 32 + (ln >> 4) * 8 + j;
            int col = nb * 16 + (ln & 15);
            v[j] = (short)f2bf(W2b2[k * C + col]);
        }
        *(s16x8*)&w2f[kb][nb][ln][0] = v;
    }

    const float gamma = 81.92f;            // 1/(2*(5/64)^2)
    const float cstep = CUT / 63.0f;
    const int nchunk = NE / 64;
    for (int ch = blockIdx.x; ch < nchunk; ch += gridDim.x) {
        __syncthreads();   // protects outL/dsh reuse across chunks (and weight prepack on iter 0)
        if (TID < 64) {
            int e = permE[ch * 64 + TID];
            float d = dist[e];
            dsh[TID] = d;
            cvsh[TID] = (d < CUT) ? 0.5f * (1.0f + __cosf((float)M_PI * d / CUT)) : 0.0f;
            n0sh[TID] = nl0[e];
            n1sh[TID] = nl1[e];
        }
        __syncthreads();

        // A-fragments for this wave's 16-edge strip: A[row=l&15][k=(l>>4)*8+j]
        {
            int e = w * 16 + (l & 15);
            float d = dsh[e], cv = cvsh[e];
            #pragma unroll
            for (int kb = 0; kb < 2; ++kb) {
                s16x8 v;
                #pragma unroll
                for (int j = 0; j < 8; ++j) {
                    int k = kb * 32 + (l >> 4) * 8 + j;
                    float dd = d - (float)k * cstep;
                    v[j] = (short)f2bf(__expf(-gamma * dd * dd) * cv);
                }
                *(s16x8*)&aF[w][kb][l][0] = v;
            }
        }
        // GEMM1: hidden(16x64) = rb(16x64) @ W2b1(64x64)
        f32x4 acc[4];
        #pragma unroll
        for (int nb = 0; nb < 4; ++nb) acc[nb] = (f32x4){0.f, 0.f, 0.f, 0.f};
        #pragma unroll
        for (int kb = 0; kb < 2; ++kb) {
            s16x8 a = *(const s16x8*)&aF[w][kb][l][0];
            #pragma unroll
            for (int nb = 0; nb < 4; ++nb) {
                s16x8 b = *(const s16x8*)&w1f[kb][nb][l][0];
                acc[nb] = __builtin_amdgcn_mfma_f32_16x16x32_bf16(a, b, acc[nb], 0, 0, 0);
            }
        }
        // ssp -> t1, rewrite into A-frag layout (reuse aF[w]; wave-local, reads are done)
        #pragma unroll
        for (int nb = 0; nb < 4; ++nb) {
            #pragma unroll
            for (int r = 0; r < 4; ++r) {
                float t = ssp(acc[nb][r]);
                int er = (l >> 4) * 4 + r;          // edge row in strip (D layout)
                int k = nb * 16 + (l & 15);         // hidden unit index
                int kb2 = k >> 5, rem = k & 31;
                aF[w][kb2][((rem >> 3) << 4) | er][rem & 7] = (short)f2bf(t);
            }
        }
        // GEMM2: out(16x128) = t1(16x64) @ W2b2(64x128)
        f32x4 acc2[8];
        #pragma unroll
        for (int nb = 0; nb < 8; ++nb) acc2[nb] = (f32x4){0.f, 0.f, 0.f, 0.f};
        #pragma unroll
        for (int kb = 0; kb < 2; ++kb) {
            s16x8 a = *(const s16x8*)&aF[w][kb][l][0];
            #pragma unroll
            for (int nb = 0; nb < 8; ++nb) {
                s16x8 b = *(const s16x8*)&w2f[kb][nb][l][0];
                acc2[nb] = __builtin_amdgcn_mfma_f32_16x16x32_bf16(a, b, acc2[nb], 0, 0, 0);
            }
        }
        // out tile to LDS (bf16)
        #pragma unroll
        for (int nb = 0; nb < 8; ++nb) {
            #pragma unroll
            for (int r = 0; r < 4; ++r) {
                int er = w * 16 + (l >> 4) * 4 + r;
                outL[er * 132 + nb * 16 + (l & 15)] = (short)acc2[nb][r] * 0 + (short)f2bf(acc2[nb][r]);
            }
        }
        __syncthreads();
        // epilogue: msg = out * h[n1], run-segmented sum over sorted n0 -> atomic add
        {
            const int c = TID & 127;
            const int e0 = (TID >> 7) * 32, e1 = e0 + 32;
            float acc3 = 0.f;
            int cur = n0sh[e0];
            #pragma unroll 8
            for (int e = e0; e < e1; ++e) {
                ushort us = (ushort)outL[e * 132 + c];
                float v = __uint_as_float((uint)us << 16) * h[(size_t)n1sh[e] * C + c];
                acc3 += v;
                int nxt = (e + 1 < e1) ? n0sh[e + 1] : -1;
                if (nxt != cur) {
                    unsafeAtomicAdd(&agg[(size_t)cur * C + c], acc3);
                    acc3 = 0.f;
                    cur = nxt;
                }
            }
        }
    }
}

// Per node r: w3 = uacc[r] @ W3b2 ; agg[nl0[r]] += h[r] * w3
__global__ __launch_bounds__(256) void k_node_final(const float* __restrict__ uacc,
                                                    const float* __restrict__ W3b2,
                                                    const float* __restrict__ h,
                                                    const int* __restrict__ nl0,
                                                    float* __restrict__ agg) {
    __shared__ float w2[64 * C];
    __shared__ float uL[8][64];
    for (int i = TID; i < 64 * C; i += 256) w2[i] = W3b2[i];
    const int eg = TID >> 5;
    const int c4 = (TID & 31) << 2;
    for (int base = blockIdx.x * 8; base < NN; base += gridDim.x * 8) {
        __syncthreads();
        if (TID < 128) {
            int row = TID >> 4, col = (TID & 15) << 2;
            *(float4*)&uL[row][col] = *(const float4*)&uacc[(size_t)(base + row) * 64 + col];
        }
        __syncthreads();
        float4 o = {0.f, 0.f, 0.f, 0.f};
        #pragma unroll
        for (int j = 0; j < 64; j += 4) {
            const float4 tv = *(const float4*)&uL[eg][j];
            const float4 wa = *(const float4*)&w2[(j + 0) * C + c4];
            const float4 wb = *(const float4*)&w2[(j + 1) * C + c4];
            const float4 wc = *(const float4*)&w2[(j + 2) * C + c4];
            const float4 wd = *(const float4*)&w2[(j + 3) * C + c4];
            o.x = fmaf(tv.x, wa.x, o.x); o.y = fmaf(tv.x, wa.y, o.y);
            o.z = fmaf(tv.x, wa.z, o.z); o.w = fmaf(tv.x, wa.w, o.w);
            o.x = fmaf(tv.y, wb.x, o.x); o.y = fmaf(tv.y, wb.y, o.y);
            o.z = fmaf(tv.y, wb.z, o.z); o.w = fmaf(tv.y, wb.w, o.w);
            o.x = fmaf(tv.z, wc.x, o.x); o.y = fmaf(tv.z, wc.y, o.y);
            o.z = fmaf(tv.z, wc.z, o.z); o.w = fmaf(tv.z, wc.w, o.w);
            o.x = fmaf(tv.w, wd.x, o.x); o.y = fmaf(tv.w, wd.y, o.y);
            o.z = fmaf(tv.w, wd.z, o.z); o.w = fmaf(tv.w, wd.w, o.w);
        }
        const int r = base + eg;
        const float4 h4 = *(const float4*)&h[(size_t)r * C + c4];
        float* dst = &agg[(size_t)nl0[r] * C + c4];
        unsafeAtomicAdd(dst + 0, o.x * h4.x);
        unsafeAtomicAdd(dst + 1, o.y * h4.y);
        unsafeAtomicAdd(dst + 2, o.z * h4.z);
        unsafeAtomicAdd(dst + 3, o.w * h4.w);
    }
}

extern "C" void kernel_launch(void* const* d_in, const int* in_sizes, int n_in,
                              void* d_out, int out_size, void* d_ws, size_t ws_size,
                              hipStream_t stream) {
    const float* features = (const float*)d_in[0];
    const float* ndist    = (const float*)d_in[1];
    const int*   nlist    = (const int*)d_in[2];
    const int*   tidx     = (const int*)d_in[3];
    const float* angles   = (const float*)d_in[4];
    const float* rij      = (const float*)d_in[5];
    const float* rik      = (const float*)d_in[6];
    const float* W_pre    = (const float*)d_in[7];
    const float* W2b1     = (const float*)d_in[8];
    const float* W2b2     = (const float*)d_in[9];
    const float* W3b1     = (const float*)d_in[10];
    const float* W3b2     = (const float*)d_in[11];
    const float* W_post   = (const float*)d_in[12];
    float* out = (float*)d_out;

    float* h    = (float*)d_ws;                   // NN*C
    float* agg  = h + (size_t)NN * C;             // NN*C
    int* histE  = (int*)(agg + (size_t)NN * C);   // NN
    int* histT  = histE + NN;                     // NN
    float* uacc = (float*)(histT + NN);           // NN*64
    int* permE  = (int*)(uacc + (size_t)NN * 64); // NE
    int* permT  = permE + NE;                     // NT
    int* startE = permT + NT;                     // NN
    int* startT = startE + NN;                    // NN
    int* curE   = startT + NN;                    // NN
    int* curT   = curE + NN;                      // NN
    const int* nl0 = nlist;
    const int* nl1 = nlist + NE;

    // zero agg + histE + histT (contiguous)
    hipLaunchKernelGGL(k_zero, dim3((NN * C + 2 * NN + 255) / 256), dim3(256), 0, stream,
                       agg, NN * C + 2 * NN);
    hipLaunchKernelGGL(k_gemm128, dim3(2500), dim3(256), 0, stream,
                       features, W_pre, h, NN);
    hipLaunchKernelGGL(k_hist, dim3(2048), dim3(256), 0, stream,
                       nl0, tidx, histE, histT);
    hipLaunchKernelGGL(k_scan2, dim3(2), dim3(1024), 0, stream,
                       histE, startE, curE, histT, startT, curT);
    hipLaunchKernelGGL(k_scatter, dim3(2048), dim3(256), 0, stream,
                       nl0, tidx, curE, curT, permE, permT);
    hipLaunchKernelGGL(k_trip_seg, dim3(2560), dim3(256), 0, stream,
                       permT, startT, histT, angles, rij, rik, W3b1, uacc);
    hipLaunchKernelGGL(k_edges_mfma, dim3(2500), dim3(256), 0, stream,
                       permE, ndist, nl0, nl1, h, W2b1, W2b2, agg);
    hipLaunchKernelGGL(k_node_final, dim3(2500), dim3(256), 0, stream,
                       uacc, W3b2, h, nl0, agg);
    hipLaunchKernelGGL(k_gemm128, dim3(2500), dim3(256), 0, stream,
                       agg, W_post, out, NN);
}

// Round 4
// 430.703 us; speedup vs baseline: 7.1506x; 1.3806x over previous
//
#include <hip/hip_runtime.h>
#include <math.h>

#define TID threadIdx.x

static constexpr int NN = 20000;
static constexpr int NE = 640000;
static constexpr int NT = 1000000;
static constexpr int C = 128;
static constexpr int E = 64;
static constexpr int LUTN = 4104;     // 4097 live rows + zero padding
static constexpr float CUT = 5.0f;
static constexpr float LN2 = 0.69314718055994530942f;

__device__ __forceinline__ float ssp(float x) {
    return fmaxf(x, 0.0f) + __logf(1.0f + __expf(-fabsf(x))) - LN2;
}

__device__ __forceinline__ ushort f2bf(float x) {
    uint u = __float_as_uint(x);
    return (ushort)((u + 0x7FFFu + ((u >> 16) & 1u)) >> 16);
}

__device__ __forceinline__ float bf2f(ushort u) {
    return __uint_as_float((uint)u << 16);
}

__global__ __launch_bounds__(256) void k_zero(float* __restrict__ p, int n) {
    int i = blockIdx.x * 256 + TID;
    if (i < n) p[i] = 0.0f;
}

// out[r][c] = sum_k A[r][k]*W[k][c], f32 out. A: nrows x 128, W: 128x128
__global__ __launch_bounds__(256) void k_gemm128(const float* __restrict__ A,
                                                 const float* __restrict__ W,
                                                 float* __restrict__ out, int nrows) {
    __shared__ float wL[C * C];
    __shared__ float aL[8][C];
    for (int i = TID; i < C * C; i += 256) wL[i] = W[i];
    const int rg = TID >> 5;
    const int c4 = (TID & 31) << 2;
    for (int base = blockIdx.x * 8; base < nrows; base += gridDim.x * 8) {
        __syncthreads();
        for (int i = TID; i < 8 * C; i += 256) {
            int r = base + (i >> 7);
            aL[i >> 7][i & 127] = (r < nrows) ? A[(size_t)r * C + (i & 127)] : 0.0f;
        }
        __syncthreads();
        float4 acc = {0.f, 0.f, 0.f, 0.f};
        #pragma unroll 16
        for (int k = 0; k < C; ++k) {
            float a = aL[rg][k];
            const float4 w4 = *(const float4*)&wL[k * C + c4];
            acc.x = fmaf(a, w4.x, acc.x);
            acc.y = fmaf(a, w4.y, acc.y);
            acc.z = fmaf(a, w4.z, acc.z);
            acc.w = fmaf(a, w4.w, acc.w);
        }
        int r = base + rg;
        if (r < nrows) *(float4*)&out[(size_t)r * C + c4] = acc;
    }
}

// Same GEMM but bf16 output (for h)
__global__ __launch_bounds__(256) void k_gemm128b(const float* __restrict__ A,
                                                  const float* __restrict__ W,
                                                  ushort* __restrict__ outB, int nrows) {
    __shared__ float wL[C * C];
    __shared__ float aL[8][C];
    for (int i = TID; i < C * C; i += 256) wL[i] = W[i];
    const int rg = TID >> 5;
    const int c4 = (TID & 31) << 2;
    for (int base = blockIdx.x * 8; base < nrows; base += gridDim.x * 8) {
        __syncthreads();
        for (int i = TID; i < 8 * C; i += 256) {
            int r = base + (i >> 7);
            aL[i >> 7][i & 127] = (r < nrows) ? A[(size_t)r * C + (i & 127)] : 0.0f;
        }
        __syncthreads();
        float4 acc = {0.f, 0.f, 0.f, 0.f};
        #pragma unroll 16
        for (int k = 0; k < C; ++k) {
            float a = aL[rg][k];
            const float4 w4 = *(const float4*)&wL[k * C + c4];
            acc.x = fmaf(a, w4.x, acc.x);
            acc.y = fmaf(a, w4.y, acc.y);
            acc.z = fmaf(a, w4.z, acc.z);
            acc.w = fmaf(a, w4.w, acc.w);
        }
        int r = base + rg;
        if (r < nrows) {
            ushort4 u = {f2bf(acc.x), f2bf(acc.y), f2bf(acc.z), f2bf(acc.w)};
            *(ushort4*)&outB[(size_t)r * C + c4] = u;
        }
    }
}

// Build lut[i][c] = (ssp(rb(i*delta)@W2b1)@W2b2)[c]; rows with d>=CUT are exactly 0.
__global__ __launch_bounds__(256) void k_lut(const float* __restrict__ W2b1,
                                             const float* __restrict__ W2b2,
                                             float* __restrict__ lut) {
    __shared__ float w1[E * E];
    __shared__ float w2[E * C];
    __shared__ float rbL[8][E];
    __shared__ float hid[8][E];
    for (int i = TID; i < E * E; i += 256) w1[i] = W2b1[i];
    for (int i = TID; i < E * C; i += 256) w2[i] = W2b2[i];
    const int jj = TID & 63;
    const int esA = TID >> 6;
    const int eg = TID >> 5;
    const int c4 = (TID & 31) << 2;
    const float gamma = 81.92f;
    const float cstep = CUT / 63.0f;
    const float delta = CUT / 4096.0f;
    const int base = blockIdx.x * 8;
    __syncthreads();
    #pragma unroll
    for (int s = 0; s < 2; ++s) {
        int es = esA + 4 * s;
        float d = (float)(base + es) * delta;
        float cv = (d < CUT) ? 0.5f * (1.0f + __cosf((float)M_PI * d / CUT)) : 0.0f;
        float dd = d - (float)jj * cstep;
        rbL[es][jj] = __expf(-gamma * dd * dd) * cv;
    }
    __syncthreads();
    #pragma unroll
    for (int s = 0; s < 2; ++s) {
        int es = esA + 4 * s;
        float a = 0.f;
        #pragma unroll 16
        for (int k = 0; k < E; ++k)
            a = fmaf(rbL[es][k], w1[k * E + jj], a);
        hid[es][jj] = ssp(a);
    }
    __syncthreads();
    float4 o = {0.f, 0.f, 0.f, 0.f};
    #pragma unroll
    for (int j = 0; j < E; ++j) {
        float t = hid[eg][j];
        const float4 w4 = *(const float4*)&w2[j * C + c4];
        o.x = fmaf(t, w4.x, o.x);
        o.y = fmaf(t, w4.y, o.y);
        o.z = fmaf(t, w4.z, o.z);
        o.w = fmaf(t, w4.w, o.w);
    }
    int row = base + eg;
    if (row < LUTN) *(float4*)&lut[(size_t)row * C + c4] = o;
}

__global__ __launch_bounds__(256) void k_hist(const int* __restrict__ nl0,
                                              const int* __restrict__ tidx,
                                              int* __restrict__ histE,
                                              int* __restrict__ histT) {
    for (int i = blockIdx.x * 256 + TID; i < NT; i += gridDim.x * 256) {
        if (i < NE) atomicAdd(&histE[nl0[i]], 1);
        atomicAdd(&histT[tidx[3 * i + 1]], 1);
    }
}

__device__ void scan_one(const int* __restrict__ hist, int* __restrict__ start,
                         int* __restrict__ cur, int n) {
    __shared__ int wsum[16];
    __shared__ int carryS;
    const int lane = TID & 63;
    const int wv = TID >> 6;
    if (TID == 0) carryS = 0;
    __syncthreads();
    for (int base = 0; base < n; base += 1024) {
        int i = base + TID;
        int v = (i < n) ? hist[i] : 0;
        int acc = v;
        #pragma unroll
        for (int off = 1; off < 64; off <<= 1) {
            int t = __shfl_up(acc, off, 64);
            if (lane >= off) acc += t;
        }
        if (lane == 63) wsum[wv] = acc;
        __syncthreads();
        int woff = 0;
        for (int w = 0; w < wv; ++w) woff += wsum[w];
        int carry = carryS;
        int excl = carry + woff + acc - v;
        if (i < n) { start[i] = excl; cur[i] = excl; }
        __syncthreads();
        if (TID == 1023) carryS = excl + v;
        __syncthreads();
    }
}

__global__ __launch_bounds__(1024) void k_scan2(const int* __restrict__ hE, int* __restrict__ sE,
                                                int* __restrict__ cE,
                                                const int* __restrict__ hT, int* __restrict__ sT,
                                                int* __restrict__ cT) {
    if (blockIdx.x == 0) scan_one(hE, sE, cE, NN);
    else                 scan_one(hT, sT, cT, NN);
}

// Counting-sort scatter that permutes the PAYLOADS (no perm index arrays).
__global__ __launch_bounds__(256) void k_scatter(const int* __restrict__ nl0,
                                                 const int* __restrict__ nl1,
                                                 const float* __restrict__ dist,
                                                 const int* __restrict__ tidx,
                                                 const float* __restrict__ angles,
                                                 const float* __restrict__ rij,
                                                 const float* __restrict__ rik,
                                                 int* __restrict__ curE, int* __restrict__ curT,
                                                 float* __restrict__ dS,
                                                 int* __restrict__ n0S, int* __restrict__ n1S,
                                                 float* __restrict__ riS,
                                                 float* __restrict__ rkS,
                                                 float* __restrict__ caS) {
    for (int i = blockIdx.x * 256 + TID; i < NT; i += gridDim.x * 256) {
        if (i < NE) {
            int n0 = nl0[i];
            int pos = atomicAdd(&curE[n0], 1);
            dS[pos] = dist[i];
            n0S[pos] = n0;
            n1S[pos] = nl1[i];
        }
        int pos = atomicAdd(&curT[tidx[3 * i + 1]], 1);
        riS[pos] = rij[i];
        rkS[pos] = rik[i];
        caS[pos] = __cosf(angles[i]);
    }
}

// One wave per node r: usum[lane] = sum over its triplets of ssp(tbf@W3b1)[lane]
__global__ __launch_bounds__(256) void k_trip_seg(const int* __restrict__ startT,
                                                  const int* __restrict__ histT,
                                                  const float* __restrict__ riS,
                                                  const float* __restrict__ rkS,
                                                  const float* __restrict__ caS,
                                                  const float* __restrict__ W3b1,
                                                  float* __restrict__ uacc) {
    const int lane = TID & 63;
    const int wv = TID >> 6;
    const float w1a = W3b1[lane];
    const float w1b = W3b1[64 + lane];
    const float w1c = W3b1[128 + lane];
    for (int r = blockIdx.x * 4 + wv; r < NN; r += gridDim.x * 4) {
        const int s0 = startT[r];
        const int cnt = histT[r];
        float usum = 0.f;
        for (int base = 0; base < cnt; base += 64) {
            const int n = min(64, cnt - base);
            float ri = 0.f, rk = 0.f, ca = 0.f;
            if (lane < n) {
                int p = s0 + base + lane;
                ri = riS[p]; rk = rkS[p]; ca = caS[p];
            }
            for (int i = 0; i < n; ++i) {
                float riB = __shfl(ri, i, 64);
                float rkB = __shfl(rk, i, 64);
                float caB = __shfl(ca, i, 64);
                float x = fmaf(riB, w1a, fmaf(rkB, w1b, caB * w1c));
                usum += ssp(x);
            }
        }
        uacc[(size_t)r * 64 + lane] = usum;
    }
}

// Hot kernel: per sorted edge, out = lerp(lut, d) * h_bf16[n1]; run-segmented sum -> agg[n0]
__global__ __launch_bounds__(256) void k_edges_lut(const float* __restrict__ dS,
                                                   const int* __restrict__ n0S,
                                                   const int* __restrict__ n1S,
                                                   const ushort* __restrict__ hB,
                                                   const float* __restrict__ lut,
                                                   float* __restrict__ agg) {
    __shared__ float dsh[256];
    __shared__ int n0sh[256];
    __shared__ int n1sh[256];
    const int c4 = (TID & 31) << 2;
    const int g = TID >> 5;                 // 8 groups x 32 edges
    const float scale = 4096.0f / CUT;
    const int nchunk = NE / 256;
    for (int ch = blockIdx.x; ch < nchunk; ch += gridDim.x) {
        __syncthreads();
        {
            int e = ch * 256 + TID;
            dsh[TID] = dS[e];
            n0sh[TID] = n0S[e];
            n1sh[TID] = n1S[e];
        }
        __syncthreads();
        float4 acc = {0.f, 0.f, 0.f, 0.f};
        int cur = n0sh[g * 32];
        #pragma unroll 4
        for (int j = 0; j < 32; ++j) {
            int e = g * 32 + j;
            float t = dsh[e] * scale;
            int idx = min((int)t, LUTN - 2);
            float fr = t - (float)idx;
            const float4 A = *(const float4*)&lut[(size_t)idx * C + c4];
            const float4 B = *(const float4*)&lut[(size_t)(idx + 1) * C + c4];
            const ushort4 hb = *(const ushort4*)&hB[(size_t)n1sh[e] * C + c4];
            float ox = fmaf(fr, B.x - A.x, A.x);
            float oy = fmaf(fr, B.y - A.y, A.y);
            float oz = fmaf(fr, B.z - A.z, A.z);
            float ow = fmaf(fr, B.w - A.w, A.w);
            acc.x = fmaf(ox, bf2f(hb.x), acc.x);
            acc.y = fmaf(oy, bf2f(hb.y), acc.y);
            acc.z = fmaf(oz, bf2f(hb.z), acc.z);
            acc.w = fmaf(ow, bf2f(hb.w), acc.w);
            int nxt = (j < 31) ? n0sh[e + 1] : -1;
            if (nxt != cur) {
                float* dst = &agg[(size_t)cur * C + c4];
                unsafeAtomicAdd(dst + 0, acc.x);
                unsafeAtomicAdd(dst + 1, acc.y);
                unsafeAtomicAdd(dst + 2, acc.z);
                unsafeAtomicAdd(dst + 3, acc.w);
                acc = (float4){0.f, 0.f, 0.f, 0.f};
                cur = nxt;
            }
        }
    }
}

// Per node r: w3 = uacc[r]@W3b2 ; agg[nl0[r]] += h[r]*w3
__global__ __launch_bounds__(256) void k_node_final(const float* __restrict__ uacc,
                                                    const float* __restrict__ W3b2,
                                                    const ushort* __restrict__ hB,
                                                    const int* __restrict__ nl0,
                                                    float* __restrict__ agg) {
    __shared__ float w2[64 * C];
    __shared__ float uL[8][64];
    for (int i = TID; i < 64 * C; i += 256) w2[i] = W3b2[i];
    const int eg = TID >> 5;
    const int c4 = (TID & 31) << 2;
    for (int base = blockIdx.x * 8; base < NN; base += gridDim.x * 8) {
        __syncthreads();
        if (TID < 128) {
            int row = TID >> 4, col = (TID & 15) << 2;
            *(float4*)&uL[row][col] = *(const float4*)&uacc[(size_t)(base + row) * 64 + col];
        }
        __syncthreads();
        float4 o = {0.f, 0.f, 0.f, 0.f};
        #pragma unroll
        for (int j = 0; j < 64; ++j) {
            float t = uL[eg][j];
            const float4 w4 = *(const float4*)&w2[j * C + c4];
            o.x = fmaf(t, w4.x, o.x);
            o.y = fmaf(t, w4.y, o.y);
            o.z = fmaf(t, w4.z, o.z);
            o.w = fmaf(t, w4.w, o.w);
        }
        const int r = base + eg;
        const ushort4 hb = *(const ushort4*)&hB[(size_t)r * C + c4];
        float* dst = &agg[(size_t)nl0[r] * C + c4];
        unsafeAtomicAdd(dst + 0, o.x * bf2f(hb.x));
        unsafeAtomicAdd(dst + 1, o.y * bf2f(hb.y));
        unsafeAtomicAdd(dst + 2, o.z * bf2f(hb.z));
        unsafeAtomicAdd(dst + 3, o.w * bf2f(hb.w));
    }
}

extern "C" void kernel_launch(void* const* d_in, const int* in_sizes, int n_in,
                              void* d_out, int out_size, void* d_ws, size_t ws_size,
                              hipStream_t stream) {
    const float* features = (const float*)d_in[0];
    const float* ndist    = (const float*)d_in[1];
    const int*   nlist    = (const int*)d_in[2];
    const int*   tidx     = (const int*)d_in[3];
    const float* angles   = (const float*)d_in[4];
    const float* rij      = (const float*)d_in[5];
    const float* rik      = (const float*)d_in[6];
    const float* W_pre    = (const float*)d_in[7];
    const float* W2b1     = (const float*)d_in[8];
    const float* W2b2     = (const float*)d_in[9];
    const float* W3b1     = (const float*)d_in[10];
    const float* W3b2     = (const float*)d_in[11];
    const float* W_post   = (const float*)d_in[12];
    float* out = (float*)d_out;

    char* w = (char*)d_ws;
    float* agg   = (float*)w;                     w += (size_t)NN * C * 4;   // 10.24 MB
    int* histE   = (int*)w;                       w += (size_t)NN * 4;
    int* histT   = (int*)w;                       w += (size_t)NN * 4;
    ushort* hB   = (ushort*)w;                    w += (size_t)NN * C * 2;   // 5.12 MB
    float* lut   = (float*)w;                     w += (size_t)LUTN * C * 4; // 2.10 MB
    float* uacc  = (float*)w;                     w += (size_t)NN * 64 * 4;  // 5.12 MB
    float* dS    = (float*)w;                     w += (size_t)NE * 4;
    int* n0S     = (int*)w;                       w += (size_t)NE * 4;
    int* n1S     = (int*)w;                       w += (size_t)NE * 4;
    float* riS   = (float*)w;                     w += (size_t)NT * 4;
    float* rkS   = (float*)w;                     w += (size_t)NT * 4;
    float* caS   = (float*)w;                     w += (size_t)NT * 4;
    int* startE  = (int*)w;                       w += (size_t)NN * 4;
    int* startT  = (int*)w;                       w += (size_t)NN * 4;
    int* curE    = (int*)w;                       w += (size_t)NN * 4;
    int* curT    = (int*)w;                       w += (size_t)NN * 4;

    const int* nl0 = nlist;
    const int* nl1 = nlist + NE;

    // zero agg + histE + histT (contiguous)
    hipLaunchKernelGGL(k_zero, dim3((NN * C + 2 * NN + 255) / 256), dim3(256), 0, stream,
                       agg, NN * C + 2 * NN);
    hipLaunchKernelGGL(k_gemm128b, dim3(320), dim3(256), 0, stream,
                       features, W_pre, hB, NN);
    hipLaunchKernelGGL(k_lut, dim3((LUTN + 7) / 8), dim3(256), 0, stream,
                       W2b1, W2b2, lut);
    hipLaunchKernelGGL(k_hist, dim3(2048), dim3(256), 0, stream,
                       nl0, tidx, histE, histT);
    hipLaunchKernelGGL(k_scan2, dim3(2), dim3(1024), 0, stream,
                       histE, startE, curE, histT, startT, curT);
    hipLaunchKernelGGL(k_scatter, dim3(2048), dim3(256), 0, stream,
                       nl0, nl1, ndist, tidx, angles, rij, rik,
                       curE, curT, dS, n0S, n1S, riS, rkS, caS);
    hipLaunchKernelGGL(k_trip_seg, dim3(2560), dim3(256), 0, stream,
                       startT, histT, riS, rkS, caS, W3b1, uacc);
    hipLaunchKernelGGL(k_edges_lut, dim3(2500), dim3(256), 0, stream,
                       dS, n0S, n1S, hB, lut, agg);
    hipLaunchKernelGGL(k_node_final, dim3(1250), dim3(256), 0, stream,
                       uacc, W3b2, hB, nl0, agg);
    hipLaunchKernelGGL(k_gemm128, dim3(320), dim3(256), 0, stream,
                       agg, W_post, out, NN);
}